// Round 13
// baseline (621.338 us; speedup 1.0000x reference)
//
#include <hip/hip_runtime.h>
#include <hip/hip_fp16.h>

#define D_IN 128
#define D_HID 64
#define N_GRAPHS 1024
#define N_CLASSES 10

#define NPB 256      // nodes per bucket (power of 2)
#define MAXNB 1024   // supports n <= 262144
#define CHUNK 16384  // edges per bin_edges block (long runs -> write combining)
#define XS_STRIDE 68 // LDS row stride (floats): 68%32=4 -> rows spread across banks

typedef __attribute__((ext_vector_type(8))) short bf16x8;
typedef __attribute__((ext_vector_type(4))) float f32x4;

__device__ __forceinline__ unsigned bf16_rne(float f) {
    unsigned u = __float_as_uint(f);
    return (u + 0x7FFF + ((u >> 16) & 1)) >> 16;
}

// ============ P1: bucket histogram (LDS-privatized) ============
__global__ __launch_bounds__(256) void hist_buckets(const int* __restrict__ dst, int nE, int NB,
                                                    int* __restrict__ bcnt) {
    __shared__ int h[MAXNB];
    for (int i = threadIdx.x; i < NB; i += 256) h[i] = 0;
    __syncthreads();
    int stride = gridDim.x * 256;
    for (int i = blockIdx.x * 256 + threadIdx.x; i < nE; i += stride)
        atomicAdd(&h[dst[i] >> 8], 1);
    __syncthreads();
    for (int i = threadIdx.x; i < NB; i += 256) {
        int c = h[i];
        if (c) atomicAdd(&bcnt[i], c);
    }
}

// ============ pack W into MFMA B-fragment order (device helper, 1024-thr) ============
template <int K>
__device__ void pack_dev(const float* __restrict__ W, short* __restrict__ hi, short* __restrict__ lo) {
    constexpr int SLOTS = (K / 32) * 4 * 64;
    for (int s = threadIdx.x; s < SLOTS; s += 1024) {
        int lane = s & 63, nf = (s >> 6) & 3, ks = s >> 8;
        int fq = lane >> 4, fr = lane & 15;
#pragma unroll
        for (int j = 0; j < 8; ++j) {
            int k = ks * 32 + fq * 8 + j;
            int c = nf * 16 + fr;
            float v = W[k * 64 + c];
            unsigned hb = bf16_rne(v);
            float hf = __uint_as_float(hb << 16);
            float l = v - hf;
            hi[s * 8 + j] = (short)hb;
            lo[s * 8 + j] = (short)bf16_rne(l);
        }
    }
}

// ============ P2 fused: block0 = bucket scan; blocks1-3 = pack W1/2/3; blocks4-11 = zero sums/gcnt ============
__global__ __launch_bounds__(1024) void fused_prep(
    const int* __restrict__ bcnt, int NB, int nE,
    int* __restrict__ boff, int* __restrict__ gcur,
    const float* __restrict__ W1, short* __restrict__ w1hi, short* __restrict__ w1lo,
    const float* __restrict__ W2, short* __restrict__ w2hi, short* __restrict__ w2lo,
    const float* __restrict__ W3, short* __restrict__ w3hi, short* __restrict__ w3lo,
    float* __restrict__ sums, float* __restrict__ gcnt) {
    __shared__ int t[1024];
    int b = blockIdx.x, tid = threadIdx.x;
    if (b == 0) {
        int v = (tid < NB) ? bcnt[tid] : 0;
        t[tid] = v;
        __syncthreads();
        for (int off = 1; off < 1024; off <<= 1) {
            int u = (tid >= off) ? t[tid - off] : 0;
            __syncthreads();
            t[tid] += u;
            __syncthreads();
        }
        int excl = t[tid] - v;
        if (tid < NB) { boff[tid] = excl; gcur[tid] = excl; }
        if (tid == 0) boff[NB] = nE;
    } else if (b == 1) {
        pack_dev<D_IN>(W1, w1hi, w1lo);
    } else if (b == 2) {
        pack_dev<D_HID>(W2, w2hi, w2lo);
    } else if (b == 3) {
        pack_dev<D_HID>(W3, w3hi, w3lo);
    } else {
        const int total = N_GRAPHS * 64;
        for (int i = (b - 4) * 1024 + tid; i < total; i += 8 * 1024) sums[i] = 0.0f;
        for (int i = (b - 4) * 1024 + tid; i < N_GRAPHS; i += 8 * 1024) gcnt[i] = 0.0f;
    }
}

// ============ P3: bin edges into bucket-contiguous packed array ============
__global__ __launch_bounds__(1024) void bin_edges(const int* __restrict__ src, const int* __restrict__ dst,
                                                  int nE, int NB, int* __restrict__ gcur,
                                                  int* __restrict__ binned) {
    __shared__ int h[MAXNB];
    __shared__ int base[MAXNB];
    int c0 = blockIdx.x * CHUNK;
    int c1 = min(nE, c0 + CHUNK);
    for (int i = threadIdx.x; i < NB; i += 1024) h[i] = 0;
    __syncthreads();
    for (int i = c0 + threadIdx.x; i < c1; i += 1024) atomicAdd(&h[dst[i] >> 8], 1);
    __syncthreads();
    for (int b = threadIdx.x; b < NB; b += 1024) {
        int c = h[b];
        base[b] = c ? atomicAdd(&gcur[b], c) : 0;
        h[b] = 0;
    }
    __syncthreads();
    for (int i = c0 + threadIdx.x; i < c1; i += 1024) {
        int d = dst[i];
        int b = d >> 8;
        int r = atomicAdd(&h[b], 1);
        binned[base[b] + r] = src[i] | ((d & 255) << 17);
    }
}

// ============ P4: per-bucket CSR finalize (rowptr, dinv, csr_src) ============
__global__ __launch_bounds__(256) void build_csr(const int* __restrict__ boff,
                                                 const int* __restrict__ binned,
                                                 int n, int nE,
                                                 int* __restrict__ rowptr, float* __restrict__ dinv,
                                                 int* __restrict__ csr_src) {
    __shared__ int cnt[NPB];
    __shared__ int soff[NPB];
    __shared__ int cur[NPB];
    int b = blockIdx.x, tid = threadIdx.x;
    int nbase = b << 8;
    int e0 = boff[b], e1 = boff[b + 1];
    cnt[tid] = 0;
    __syncthreads();
    for (int i = e0 + tid; i < e1; i += 256) atomicAdd(&cnt[binned[i] >> 17], 1);
    __syncthreads();
    int v = cnt[tid];
    soff[tid] = v;
    __syncthreads();
    for (int off = 1; off < 256; off <<= 1) {
        int u = (tid >= off) ? soff[tid - off] : 0;
        __syncthreads();
        soff[tid] += u;
        __syncthreads();
    }
    int excl = soff[tid] - v;
    __syncthreads();
    soff[tid] = excl;
    cur[tid] = 0;
    int node = nbase + tid;
    if (node < n) {
        rowptr[node] = e0 + excl;
        dinv[node] = 1.0f / sqrtf((float)(cnt[tid] + 1));
    }
    if (b == 0 && tid == 0) rowptr[n] = nE;
    __syncthreads();
    for (int i = e0 + tid; i < e1; i += 256) {
        int e = binned[i];
        int ld = e >> 17;
        int r = atomicAdd(&cur[ld], 1);
        csr_src[e0 + soff[ld] + r] = e & 0x1FFFF;
    }
}

// ============ MFMA GEMM (layer 1): H[n,64] = X @ W1, fp16 out ============
template <int K>
__global__ __launch_bounds__(256) void gemm_mfma(
    const float* __restrict__ X, const short* __restrict__ whi, const short* __restrict__ wlo,
    __half* __restrict__ H, int n) {
    constexpr int KS = K / 32;
    int wave = threadIdx.x >> 6, lane = threadIdx.x & 63;
    int fr = lane & 15, fq = lane >> 4;
    int rowbase = blockIdx.x * 64 + wave * 16;
    int rclamp = min(rowbase + fr, n - 1);
    f32x4 acc[4] = {{0,0,0,0},{0,0,0,0},{0,0,0,0},{0,0,0,0}};
#pragma unroll
    for (int ks = 0; ks < KS; ++ks) {
        const float* xp = X + (size_t)rclamp * K + ks * 32 + fq * 8;
        float xv[8];
        *(f32x4*)&xv[0] = *(const f32x4*)xp;
        *(f32x4*)&xv[4] = *(const f32x4*)(xp + 4);
        bf16x8 ahi, alo;
#pragma unroll
        for (int j = 0; j < 8; ++j) {
            unsigned hb = bf16_rne(xv[j]);
            float hf = __uint_as_float(hb << 16);
            ahi[j] = (short)hb;
            alo[j] = (short)bf16_rne(xv[j] - hf);
        }
        const short* whp = whi + (size_t)(ks * 4) * 64 * 8 + lane * 8;
        const short* wlp = wlo + (size_t)(ks * 4) * 64 * 8 + lane * 8;
#pragma unroll
        for (int nf = 0; nf < 4; ++nf) {
            bf16x8 bhi = *(const bf16x8*)(whp + nf * 512);
            bf16x8 blo = *(const bf16x8*)(wlp + nf * 512);
            acc[nf] = __builtin_amdgcn_mfma_f32_16x16x32_bf16(ahi, bhi, acc[nf], 0, 0, 0);
            acc[nf] = __builtin_amdgcn_mfma_f32_16x16x32_bf16(alo, bhi, acc[nf], 0, 0, 0);
            acc[nf] = __builtin_amdgcn_mfma_f32_16x16x32_bf16(ahi, blo, acc[nf], 0, 0, 0);
        }
    }
#pragma unroll
    for (int nf = 0; nf < 4; ++nf) {
#pragma unroll
        for (int reg = 0; reg < 4; ++reg) {
            int r = rowbase + fq * 4 + reg;
            if (r < n) H[((size_t)r << 6) + nf * 16 + fr] = __float2half(acc[nf][reg]);
        }
    }
}

// ============ fused gather + GEMM (layers 2,3) ============
// Stage 1: block gathers its 64 nodes' aggregated features into LDS (r12 gather body).
// Stage 2: MFMA on LDS tile with bias+relu on load; fp16 out to Hout.
__global__ __launch_bounds__(256) void gather_gemm(
    const int* __restrict__ rowptr, const int* __restrict__ csr_src,
    const float* __restrict__ dinv, const __half* __restrict__ A,
    const short* __restrict__ whi, const short* __restrict__ wlo,
    const float* __restrict__ bias, __half* __restrict__ Hout, int n) {
    __shared__ float xs[64 * XS_STRIDE];
    int tid = threadIdx.x;
    int wave = tid >> 6, lane = tid & 63;
    int slot = lane >> 3, fl = lane & 7;
    int rowbase = blockIdx.x * 64;
    // ---- stage 1: gather 16 nodes per wave ----
    for (int i = 0; i < 16; ++i) {
        int lr = (wave << 4) + i;
        int d = rowbase + lr;
        float acc[8];
#pragma unroll
        for (int j = 0; j < 8; ++j) acc[j] = 0.0f;
        if (d < n) {
            float dd = dinv[d];
            int e0 = rowptr[d], e1 = rowptr[d + 1];
            if (slot == 0) {
                uint4 q = *(const uint4*)(A + ((size_t)d << 6) + (fl << 3));
                const __half2* hp = (const __half2*)&q;
                float w = dd * dd;
#pragma unroll
                for (int j = 0; j < 4; ++j) {
                    float2 f = __half22float2(hp[j]);
                    acc[2 * j] = w * f.x;
                    acc[2 * j + 1] = w * f.y;
                }
            }
            int e = e0 + slot;
            for (; e + 8 < e1; e += 16) {
                int s0 = csr_src[e], s1 = csr_src[e + 8];
                float w0 = dd * dinv[s0], w1 = dd * dinv[s1];
                uint4 q0 = *(const uint4*)(A + ((size_t)s0 << 6) + (fl << 3));
                uint4 q1 = *(const uint4*)(A + ((size_t)s1 << 6) + (fl << 3));
                const __half2* h0 = (const __half2*)&q0;
                const __half2* h1 = (const __half2*)&q1;
#pragma unroll
                for (int j = 0; j < 4; ++j) {
                    float2 f0 = __half22float2(h0[j]);
                    float2 f1 = __half22float2(h1[j]);
                    acc[2 * j]     = fmaf(w0, f0.x, acc[2 * j]);
                    acc[2 * j + 1] = fmaf(w0, f0.y, acc[2 * j + 1]);
                    acc[2 * j]     = fmaf(w1, f1.x, acc[2 * j]);
                    acc[2 * j + 1] = fmaf(w1, f1.y, acc[2 * j + 1]);
                }
            }
            if (e < e1) {
                int s = csr_src[e];
                float w = dd * dinv[s];
                uint4 q = *(const uint4*)(A + ((size_t)s << 6) + (fl << 3));
                const __half2* hp = (const __half2*)&q;
#pragma unroll
                for (int j = 0; j < 4; ++j) {
                    float2 f = __half22float2(hp[j]);
                    acc[2 * j]     = fmaf(w, f.x, acc[2 * j]);
                    acc[2 * j + 1] = fmaf(w, f.y, acc[2 * j + 1]);
                }
            }
#pragma unroll
            for (int m = 8; m <= 32; m <<= 1)
#pragma unroll
                for (int j = 0; j < 8; ++j) acc[j] += __shfl_xor(acc[j], m);
        }
        if (slot == 0) {
            float* xp = &xs[lr * XS_STRIDE + (fl << 3)];
            *(f32x4*)xp = *(f32x4*)&acc[0];
            *(f32x4*)(xp + 4) = *(f32x4*)&acc[4];
        }
    }
    __syncthreads();
    // ---- stage 2: GEMM from LDS (K=64), bias+relu on load ----
    int fr = lane & 15, fq = lane >> 4;
    f32x4 acc4[4] = {{0,0,0,0},{0,0,0,0},{0,0,0,0},{0,0,0,0}};
#pragma unroll
    for (int ks = 0; ks < 2; ++ks) {
        int kbase = ks * 32 + fq * 8;
        const float* xp = &xs[((wave << 4) + fr) * XS_STRIDE + kbase];
        float xv[8];
        *(f32x4*)&xv[0] = *(const f32x4*)xp;
        *(f32x4*)&xv[4] = *(const f32x4*)(xp + 4);
        const float* bp = bias + kbase;
#pragma unroll
        for (int j = 0; j < 8; ++j) xv[j] = fmaxf(xv[j] + bp[j], 0.0f);
        bf16x8 ahi, alo;
#pragma unroll
        for (int j = 0; j < 8; ++j) {
            unsigned hb = bf16_rne(xv[j]);
            float hf = __uint_as_float(hb << 16);
            ahi[j] = (short)hb;
            alo[j] = (short)bf16_rne(xv[j] - hf);
        }
        const short* whp = whi + (size_t)(ks * 4) * 64 * 8 + lane * 8;
        const short* wlp = wlo + (size_t)(ks * 4) * 64 * 8 + lane * 8;
#pragma unroll
        for (int nf = 0; nf < 4; ++nf) {
            bf16x8 bhi = *(const bf16x8*)(whp + nf * 512);
            bf16x8 blo = *(const bf16x8*)(wlp + nf * 512);
            acc4[nf] = __builtin_amdgcn_mfma_f32_16x16x32_bf16(ahi, bhi, acc4[nf], 0, 0, 0);
            acc4[nf] = __builtin_amdgcn_mfma_f32_16x16x32_bf16(alo, bhi, acc4[nf], 0, 0, 0);
            acc4[nf] = __builtin_amdgcn_mfma_f32_16x16x32_bf16(ahi, blo, acc4[nf], 0, 0, 0);
        }
    }
#pragma unroll
    for (int nf = 0; nf < 4; ++nf) {
#pragma unroll
        for (int reg = 0; reg < 4; ++reg) {
            int r = rowbase + (wave << 4) + fq * 4 + reg;
            if (r < n) Hout[((size_t)r << 6) + nf * 16 + fr] = __float2half(acc4[nf][reg]);
        }
    }
}

// ============ fused gather + mean-pool accumulate (layer 3 output) ============
__global__ __launch_bounds__(256) void gather_pool(
    const int* __restrict__ rowptr, const int* __restrict__ csr_src,
    const float* __restrict__ dinv, const __half* __restrict__ A,
    const int* __restrict__ batch, float* __restrict__ sums,
    float* __restrict__ gcnt, int n) {
    int gtid = blockIdx.x * 256 + threadIdx.x;
    int wid = gtid >> 6, lane = gtid & 63;
    int nw = (gridDim.x * 256) >> 6;
    int slot = lane >> 3, fl = lane & 7;
    for (int d = wid; d < n; d += nw) {
        float dd = dinv[d];
        int e0 = rowptr[d], e1 = rowptr[d + 1];
        float acc[8];
#pragma unroll
        for (int j = 0; j < 8; ++j) acc[j] = 0.0f;
        if (slot == 0) {
            uint4 q = *(const uint4*)(A + ((size_t)d << 6) + (fl << 3));
            const __half2* hp = (const __half2*)&q;
            float w = dd * dd;
#pragma unroll
            for (int j = 0; j < 4; ++j) {
                float2 f = __half22float2(hp[j]);
                acc[2 * j] = w * f.x;
                acc[2 * j + 1] = w * f.y;
            }
        }
        int e = e0 + slot;
        for (; e + 8 < e1; e += 16) {
            int s0 = csr_src[e], s1 = csr_src[e + 8];
            float w0 = dd * dinv[s0], w1 = dd * dinv[s1];
            uint4 q0 = *(const uint4*)(A + ((size_t)s0 << 6) + (fl << 3));
            uint4 q1 = *(const uint4*)(A + ((size_t)s1 << 6) + (fl << 3));
            const __half2* h0 = (const __half2*)&q0;
            const __half2* h1 = (const __half2*)&q1;
#pragma unroll
            for (int j = 0; j < 4; ++j) {
                float2 f0 = __half22float2(h0[j]);
                float2 f1 = __half22float2(h1[j]);
                acc[2 * j]     = fmaf(w0, f0.x, acc[2 * j]);
                acc[2 * j + 1] = fmaf(w0, f0.y, acc[2 * j + 1]);
                acc[2 * j]     = fmaf(w1, f1.x, acc[2 * j]);
                acc[2 * j + 1] = fmaf(w1, f1.y, acc[2 * j + 1]);
            }
        }
        if (e < e1) {
            int s = csr_src[e];
            float w = dd * dinv[s];
            uint4 q = *(const uint4*)(A + ((size_t)s << 6) + (fl << 3));
            const __half2* hp = (const __half2*)&q;
#pragma unroll
            for (int j = 0; j < 4; ++j) {
                float2 f = __half22float2(hp[j]);
                acc[2 * j]     = fmaf(w, f.x, acc[2 * j]);
                acc[2 * j + 1] = fmaf(w, f.y, acc[2 * j + 1]);
            }
        }
#pragma unroll
        for (int m = 8; m <= 32; m <<= 1)
#pragma unroll
            for (int j = 0; j < 8; ++j) acc[j] += __shfl_xor(acc[j], m);
        if (slot == 0) {
            int g = batch[d];
            float* sp = &sums[((size_t)g << 6) + (fl << 3)];
#pragma unroll
            for (int j = 0; j < 8; ++j) atomicAdd(sp + j, acc[j]);
            if (fl == 0) atomicAdd(&gcnt[g], 1.0f);
        }
    }
}

// ============ final: out[g,c] = ((sums[g]/cnt[g]) + b3) . Wl[:,c] + bl[c] ============
__global__ void final_linear(const float* __restrict__ sums, const float* __restrict__ gcnt,
                             const float* __restrict__ b3,
                             const float* __restrict__ Wl, const float* __restrict__ bl,
                             float* __restrict__ out) {
    int idx = blockIdx.x * blockDim.x + threadIdx.x;
    if (idx >= N_GRAPHS * N_CLASSES) return;
    int g = idx / N_CLASSES, c = idx - g * N_CLASSES;
    float inv = 1.0f / fmaxf(gcnt[g], 1.0f);
    float acc = bl[c];
#pragma unroll
    for (int d = 0; d < D_HID; ++d)
        acc = fmaf(sums[(g << 6) + d] * inv + b3[d], Wl[d * N_CLASSES + c], acc);
    out[idx] = acc;
}

extern "C" void kernel_launch(void* const* d_in, const int* in_sizes, int n_in,
                              void* d_out, int out_size, void* d_ws, size_t ws_size,
                              hipStream_t stream) {
    const float* x     = (const float*)d_in[0];
    const int*   ei    = (const int*)d_in[1];
    const int*   batch = (const int*)d_in[2];
    const float* W1 = (const float*)d_in[3];
    const float* b1 = (const float*)d_in[4];
    const float* W2 = (const float*)d_in[5];
    const float* b2 = (const float*)d_in[6];
    const float* W3 = (const float*)d_in[7];
    const float* b3 = (const float*)d_in[8];
    const float* Wl = (const float*)d_in[9];
    const float* bl = (const float*)d_in[10];

    int n = in_sizes[0] / D_IN;
    int E = in_sizes[1] / 2;
    const int* src = ei;
    const int* dst = ei + E;
    int NB = (n + NPB - 1) / NPB;

    size_t off = 0;
    auto alloc = [&](size_t bytes) {
        void* p = (char*)d_ws + off;
        off += ((bytes + 255) & ~(size_t)255);
        return p;
    };
    int*    rowptr  = (int*)alloc(((size_t)n + 1) * 4);
    int*    bcnt    = (int*)alloc(MAXNB * 4);
    int*    boff    = (int*)alloc((MAXNB + 1) * 4);
    int*    gcur    = (int*)alloc(MAXNB * 4);
    int*    binned  = (int*)alloc((size_t)E * 4);      // aliased below as A (fp16 n*64)
    int*    csr_src = (int*)alloc((size_t)E * 4);
    float*  dinv    = (float*)alloc((size_t)n * 4);
    __half* C       = (__half*)alloc((size_t)n * 64 * 2);  // ping-pong fp16 features
    float*  sums    = (float*)alloc(N_GRAPHS * 64 * 4);
    float*  gcnt    = (float*)alloc(N_GRAPHS * 4);
    short*  w1hi    = (short*)alloc(4 * 4 * 64 * 8 * 2);
    short*  w1lo    = (short*)alloc(4 * 4 * 64 * 8 * 2);
    short*  w2hi    = (short*)alloc(2 * 4 * 64 * 8 * 2);
    short*  w2lo    = (short*)alloc(2 * 4 * 64 * 8 * 2);
    short*  w3hi    = (short*)alloc(2 * 4 * 64 * 8 * 2);
    short*  w3lo    = (short*)alloc(2 * 4 * 64 * 8 * 2);
    __half* A       = (__half*)binned;  // binned dead (after build_csr) before A is written

    int blk = 256;
    int gBin  = (E + CHUNK - 1) / CHUNK;
    int gGemm = (n + 63) / 64;

    // ---- CSR build + weight pack + output-accumulator zeroing ----
    hipMemsetAsync(bcnt, 0, MAXNB * sizeof(int), stream);
    hist_buckets<<<1024, blk, 0, stream>>>(dst, E, NB, bcnt);
    fused_prep<<<12, 1024, 0, stream>>>(bcnt, NB, E, boff, gcur,
                                        W1, w1hi, w1lo, W2, w2hi, w2lo, W3, w3hi, w3lo,
                                        sums, gcnt);
    bin_edges<<<gBin, 1024, 0, stream>>>(src, dst, E, NB, gcur, binned);
    build_csr<<<NB, blk, 0, stream>>>(boff, binned, n, E, rowptr, dinv, csr_src);

    // ---- layer 1: X @ W1 -> A (fp16) ----
    gemm_mfma<D_IN><<<gGemm, blk, 0, stream>>>(x, w1hi, w1lo, A, n);

    // ---- layer 2: gather(A) -> LDS -> @W2 -> C ----
    gather_gemm<<<gGemm, blk, 0, stream>>>(rowptr, csr_src, dinv, A, w2hi, w2lo, b1, C, n);

    // ---- layer 3: gather(C) -> LDS -> @W3 -> A ----
    gather_gemm<<<gGemm, blk, 0, stream>>>(rowptr, csr_src, dinv, C, w3hi, w3lo, b2, A, n);

    // ---- gather(A) + mean-pool accumulate ----
    gather_pool<<<2048, blk, 0, stream>>>(rowptr, csr_src, dinv, A, batch, sums, gcnt, n);

    // ---- final linear (b3 folded in) ----
    final_linear<<<(N_GRAPHS * N_CLASSES + blk - 1) / blk, blk, 0, stream>>>(
        sums, gcnt, b3, Wl, bl, (float*)d_out);
}

// Round 14
// 348.178 us; speedup vs baseline: 1.7845x; 1.7845x over previous
//
#include <hip/hip_runtime.h>
#include <hip/hip_fp16.h>

#define D_IN 128
#define D_HID 64
#define N_GRAPHS 1024
#define N_CLASSES 10

#define NPB 256      // nodes per bucket (power of 2)
#define MAXNB 1024   // supports n <= 262144
#define CHUNK 16384  // edges per bin_edges block (long runs -> write combining)

typedef __attribute__((ext_vector_type(8))) short bf16x8;
typedef __attribute__((ext_vector_type(4))) float f32x4;

__device__ __forceinline__ unsigned bf16_rne(float f) {
    unsigned u = __float_as_uint(f);
    return (u + 0x7FFF + ((u >> 16) & 1)) >> 16;
}

// ============ P1: bucket histogram (LDS-privatized) ============
__global__ __launch_bounds__(256) void hist_buckets(const int* __restrict__ dst, int nE, int NB,
                                                    int* __restrict__ bcnt) {
    __shared__ int h[MAXNB];
    for (int i = threadIdx.x; i < NB; i += 256) h[i] = 0;
    __syncthreads();
    int stride = gridDim.x * 256;
    for (int i = blockIdx.x * 256 + threadIdx.x; i < nE; i += stride)
        atomicAdd(&h[dst[i] >> 8], 1);
    __syncthreads();
    for (int i = threadIdx.x; i < NB; i += 256) {
        int c = h[i];
        if (c) atomicAdd(&bcnt[i], c);
    }
}

// ============ pack W into MFMA B-fragment order (device helper, 1024-thr) ============
template <int K>
__device__ void pack_dev(const float* __restrict__ W, short* __restrict__ hi, short* __restrict__ lo) {
    constexpr int SLOTS = (K / 32) * 4 * 64;
    for (int s = threadIdx.x; s < SLOTS; s += 1024) {
        int lane = s & 63, nf = (s >> 6) & 3, ks = s >> 8;
        int fq = lane >> 4, fr = lane & 15;
#pragma unroll
        for (int j = 0; j < 8; ++j) {
            int k = ks * 32 + fq * 8 + j;
            int c = nf * 16 + fr;
            float v = W[k * 64 + c];
            unsigned hb = bf16_rne(v);
            float hf = __uint_as_float(hb << 16);
            float l = v - hf;
            hi[s * 8 + j] = (short)hb;
            lo[s * 8 + j] = (short)bf16_rne(l);
        }
    }
}

// ============ P2 fused: block0 = bucket scan; blocks1-3 = pack W1/2/3; blocks4-11 = zero sums/gcnt ============
__global__ __launch_bounds__(1024) void fused_prep(
    const int* __restrict__ bcnt, int NB, int nE,
    int* __restrict__ boff, int* __restrict__ gcur,
    const float* __restrict__ W1, short* __restrict__ w1hi, short* __restrict__ w1lo,
    const float* __restrict__ W2, short* __restrict__ w2hi, short* __restrict__ w2lo,
    const float* __restrict__ W3, short* __restrict__ w3hi, short* __restrict__ w3lo,
    float* __restrict__ sums, float* __restrict__ gcnt) {
    __shared__ int t[1024];
    int b = blockIdx.x, tid = threadIdx.x;
    if (b == 0) {
        int v = (tid < NB) ? bcnt[tid] : 0;
        t[tid] = v;
        __syncthreads();
        for (int off = 1; off < 1024; off <<= 1) {
            int u = (tid >= off) ? t[tid - off] : 0;
            __syncthreads();
            t[tid] += u;
            __syncthreads();
        }
        int excl = t[tid] - v;
        if (tid < NB) { boff[tid] = excl; gcur[tid] = excl; }
        if (tid == 0) boff[NB] = nE;
    } else if (b == 1) {
        pack_dev<D_IN>(W1, w1hi, w1lo);
    } else if (b == 2) {
        pack_dev<D_HID>(W2, w2hi, w2lo);
    } else if (b == 3) {
        pack_dev<D_HID>(W3, w3hi, w3lo);
    } else {
        const int total = N_GRAPHS * 64;
        for (int i = (b - 4) * 1024 + tid; i < total; i += 8 * 1024) sums[i] = 0.0f;
        for (int i = (b - 4) * 1024 + tid; i < N_GRAPHS; i += 8 * 1024) gcnt[i] = 0.0f;
    }
}

// ============ P3: bin edges into bucket-contiguous packed array ============
__global__ __launch_bounds__(1024) void bin_edges(const int* __restrict__ src, const int* __restrict__ dst,
                                                  int nE, int NB, int* __restrict__ gcur,
                                                  int* __restrict__ binned) {
    __shared__ int h[MAXNB];
    __shared__ int base[MAXNB];
    int c0 = blockIdx.x * CHUNK;
    int c1 = min(nE, c0 + CHUNK);
    for (int i = threadIdx.x; i < NB; i += 1024) h[i] = 0;
    __syncthreads();
    for (int i = c0 + threadIdx.x; i < c1; i += 1024) atomicAdd(&h[dst[i] >> 8], 1);
    __syncthreads();
    for (int b = threadIdx.x; b < NB; b += 1024) {
        int c = h[b];
        base[b] = c ? atomicAdd(&gcur[b], c) : 0;
        h[b] = 0;
    }
    __syncthreads();
    for (int i = c0 + threadIdx.x; i < c1; i += 1024) {
        int d = dst[i];
        int b = d >> 8;
        int r = atomicAdd(&h[b], 1);
        binned[base[b] + r] = src[i] | ((d & 255) << 17);
    }
}

// ============ P4: per-bucket CSR finalize (rowptr, dinv, csr_src) ============
__global__ __launch_bounds__(256) void build_csr(const int* __restrict__ boff,
                                                 const int* __restrict__ binned,
                                                 int n, int nE,
                                                 int* __restrict__ rowptr, float* __restrict__ dinv,
                                                 int* __restrict__ csr_src) {
    __shared__ int cnt[NPB];
    __shared__ int soff[NPB];
    __shared__ int cur[NPB];
    int b = blockIdx.x, tid = threadIdx.x;
    int nbase = b << 8;
    int e0 = boff[b], e1 = boff[b + 1];
    cnt[tid] = 0;
    __syncthreads();
    for (int i = e0 + tid; i < e1; i += 256) atomicAdd(&cnt[binned[i] >> 17], 1);
    __syncthreads();
    int v = cnt[tid];
    soff[tid] = v;
    __syncthreads();
    for (int off = 1; off < 256; off <<= 1) {
        int u = (tid >= off) ? soff[tid - off] : 0;
        __syncthreads();
        soff[tid] += u;
        __syncthreads();
    }
    int excl = soff[tid] - v;
    __syncthreads();
    soff[tid] = excl;
    cur[tid] = 0;
    int node = nbase + tid;
    if (node < n) {
        rowptr[node] = e0 + excl;
        dinv[node] = 1.0f / sqrtf((float)(cnt[tid] + 1));
    }
    if (b == 0 && tid == 0) rowptr[n] = nE;
    __syncthreads();
    for (int i = e0 + tid; i < e1; i += 256) {
        int e = binned[i];
        int ld = e >> 17;
        int r = atomicAdd(&cur[ld], 1);
        csr_src[e0 + soff[ld] + r] = e & 0x1FFFF;
    }
}

// ============ MFMA GEMM: H[n,64] = act(X + bias) @ W[K,64], fp16 out ============
template <int K>
__global__ __launch_bounds__(256) void gemm_mfma(
    const float* __restrict__ X, const short* __restrict__ whi, const short* __restrict__ wlo,
    const float* __restrict__ bias, int relu, __half* __restrict__ H, int n) {
    constexpr int KS = K / 32;
    int wave = threadIdx.x >> 6, lane = threadIdx.x & 63;
    int fr = lane & 15, fq = lane >> 4;
    int rowbase = blockIdx.x * 64 + wave * 16;
    int rclamp = min(rowbase + fr, n - 1);
    f32x4 acc[4] = {{0,0,0,0},{0,0,0,0},{0,0,0,0},{0,0,0,0}};
#pragma unroll
    for (int ks = 0; ks < KS; ++ks) {
        const float* xp = X + (size_t)rclamp * K + ks * 32 + fq * 8;
        float xv[8];
        *(f32x4*)&xv[0] = *(const f32x4*)xp;
        *(f32x4*)&xv[4] = *(const f32x4*)(xp + 4);
        if (bias != nullptr) {
            const float* bp = bias + ks * 32 + fq * 8;
#pragma unroll
            for (int j = 0; j < 8; ++j) {
                float v = xv[j] + bp[j];
                if (relu) v = fmaxf(v, 0.0f);
                xv[j] = v;
            }
        }
        bf16x8 ahi, alo;
#pragma unroll
        for (int j = 0; j < 8; ++j) {
            unsigned hb = bf16_rne(xv[j]);
            float hf = __uint_as_float(hb << 16);
            ahi[j] = (short)hb;
            alo[j] = (short)bf16_rne(xv[j] - hf);
        }
        const short* whp = whi + (size_t)(ks * 4) * 64 * 8 + lane * 8;
        const short* wlp = wlo + (size_t)(ks * 4) * 64 * 8 + lane * 8;
#pragma unroll
        for (int nf = 0; nf < 4; ++nf) {
            bf16x8 bhi = *(const bf16x8*)(whp + nf * 512);
            bf16x8 blo = *(const bf16x8*)(wlp + nf * 512);
            acc[nf] = __builtin_amdgcn_mfma_f32_16x16x32_bf16(ahi, bhi, acc[nf], 0, 0, 0);
            acc[nf] = __builtin_amdgcn_mfma_f32_16x16x32_bf16(alo, bhi, acc[nf], 0, 0, 0);
            acc[nf] = __builtin_amdgcn_mfma_f32_16x16x32_bf16(ahi, blo, acc[nf], 0, 0, 0);
        }
    }
#pragma unroll
    for (int nf = 0; nf < 4; ++nf) {
#pragma unroll
        for (int reg = 0; reg < 4; ++reg) {
            int r = rowbase + fq * 4 + reg;
            if (r < n) H[((size_t)r << 6) + nf * 16 + fr] = __float2half(acc[nf][reg]);
        }
    }
}

// ============ CSR gather aggregation (fp16 A rows, fp32 accumulate) ============
// 8 lanes/edge x 16 B (dwordx4), 8 edge-slots/wave, unroll 2, butterfly reduce
__global__ __launch_bounds__(256) void gather_agg(
    const int* __restrict__ rowptr, const int* __restrict__ csr_src,
    const float* __restrict__ dinv, const __half* __restrict__ A,
    float* __restrict__ B, int n) {
    int gtid = blockIdx.x * 256 + threadIdx.x;
    int wid = gtid >> 6, lane = gtid & 63;
    int nw = (gridDim.x * 256) >> 6;
    int slot = lane >> 3, fl = lane & 7;   // fl: which 8-feature group (16 B)
    for (int d = wid; d < n; d += nw) {
        float dd = dinv[d];
        int e0 = rowptr[d], e1 = rowptr[d + 1];
        float acc[8];
#pragma unroll
        for (int j = 0; j < 8; ++j) acc[j] = 0.0f;
        if (slot == 0) {
            uint4 q = *(const uint4*)(A + ((size_t)d << 6) + (fl << 3));
            const __half2* hp = (const __half2*)&q;
            float w = dd * dd;
#pragma unroll
            for (int j = 0; j < 4; ++j) {
                float2 f = __half22float2(hp[j]);
                acc[2 * j] = w * f.x;
                acc[2 * j + 1] = w * f.y;
            }
        }
        int e = e0 + slot;
        for (; e + 8 < e1; e += 16) {
            int s0 = csr_src[e], s1 = csr_src[e + 8];
            float w0 = dd * dinv[s0], w1 = dd * dinv[s1];
            uint4 q0 = *(const uint4*)(A + ((size_t)s0 << 6) + (fl << 3));
            uint4 q1 = *(const uint4*)(A + ((size_t)s1 << 6) + (fl << 3));
            const __half2* h0 = (const __half2*)&q0;
            const __half2* h1 = (const __half2*)&q1;
#pragma unroll
            for (int j = 0; j < 4; ++j) {
                float2 f0 = __half22float2(h0[j]);
                float2 f1 = __half22float2(h1[j]);
                acc[2 * j]     = fmaf(w0, f0.x, acc[2 * j]);
                acc[2 * j + 1] = fmaf(w0, f0.y, acc[2 * j + 1]);
                acc[2 * j]     = fmaf(w1, f1.x, acc[2 * j]);
                acc[2 * j + 1] = fmaf(w1, f1.y, acc[2 * j + 1]);
            }
        }
        if (e < e1) {
            int s = csr_src[e];
            float w = dd * dinv[s];
            uint4 q = *(const uint4*)(A + ((size_t)s << 6) + (fl << 3));
            const __half2* hp = (const __half2*)&q;
#pragma unroll
            for (int j = 0; j < 4; ++j) {
                float2 f = __half22float2(hp[j]);
                acc[2 * j]     = fmaf(w, f.x, acc[2 * j]);
                acc[2 * j + 1] = fmaf(w, f.y, acc[2 * j + 1]);
            }
        }
#pragma unroll
        for (int m = 8; m <= 32; m <<= 1)
#pragma unroll
            for (int j = 0; j < 8; ++j) acc[j] += __shfl_xor(acc[j], m);
        if (slot == 0) {
            float* bp = B + ((size_t)d << 6) + (fl << 3);
            *(f32x4*)bp = *(f32x4*)&acc[0];
            *(f32x4*)(bp + 4) = *(f32x4*)&acc[4];
        }
    }
}

// ============ mean pool (run-length over sorted batch) ============
__global__ __launch_bounds__(256) void pool_nodes(
    const float* __restrict__ B,
    const int* __restrict__ batch, float* __restrict__ sums,
    float* __restrict__ gcnt, int n, int chunk) {
    int gtid = blockIdx.x * blockDim.x + threadIdx.x;
    int wid = gtid >> 6, lane = gtid & 63;
    int start = wid * chunk;
    if (start >= n) return;
    int end = min(n, start + chunk);
    int curg = batch[start];
    float acc = 0.0f;
    int cl = 0;
    for (int node = start; node < end; ++node) {
        int g = batch[node];
        if (g != curg) {
            atomicAdd(&sums[((size_t)curg << 6) + lane], acc);
            if (lane == 0) atomicAdd(&gcnt[curg], (float)cl);
            acc = 0.0f; cl = 0; curg = g;
        }
        acc += B[((size_t)node << 6) + lane];
        ++cl;
    }
    atomicAdd(&sums[((size_t)curg << 6) + lane], acc);
    if (lane == 0) atomicAdd(&gcnt[curg], (float)cl);
}

// ============ final: out[g,c] = ((sums[g]/cnt[g]) + b3) . Wl[:,c] + bl[c] ============
__global__ void final_linear(const float* __restrict__ sums, const float* __restrict__ gcnt,
                             const float* __restrict__ b3,
                             const float* __restrict__ Wl, const float* __restrict__ bl,
                             float* __restrict__ out) {
    int idx = blockIdx.x * blockDim.x + threadIdx.x;
    if (idx >= N_GRAPHS * N_CLASSES) return;
    int g = idx / N_CLASSES, c = idx - g * N_CLASSES;
    float inv = 1.0f / fmaxf(gcnt[g], 1.0f);
    float acc = bl[c];
#pragma unroll
    for (int d = 0; d < D_HID; ++d)
        acc = fmaf(sums[(g << 6) + d] * inv + b3[d], Wl[d * N_CLASSES + c], acc);
    out[idx] = acc;
}

extern "C" void kernel_launch(void* const* d_in, const int* in_sizes, int n_in,
                              void* d_out, int out_size, void* d_ws, size_t ws_size,
                              hipStream_t stream) {
    const float* x     = (const float*)d_in[0];
    const int*   ei    = (const int*)d_in[1];
    const int*   batch = (const int*)d_in[2];
    const float* W1 = (const float*)d_in[3];
    const float* b1 = (const float*)d_in[4];
    const float* W2 = (const float*)d_in[5];
    const float* b2 = (const float*)d_in[6];
    const float* W3 = (const float*)d_in[7];
    const float* b3 = (const float*)d_in[8];
    const float* Wl = (const float*)d_in[9];
    const float* bl = (const float*)d_in[10];

    int n = in_sizes[0] / D_IN;
    int E = in_sizes[1] / 2;
    const int* src = ei;
    const int* dst = ei + E;
    int NB = (n + NPB - 1) / NPB;

    size_t off = 0;
    auto alloc = [&](size_t bytes) {
        void* p = (char*)d_ws + off;
        off += ((bytes + 255) & ~(size_t)255);
        return p;
    };
    int*    rowptr  = (int*)alloc(((size_t)n + 1) * 4);
    int*    bcnt    = (int*)alloc(MAXNB * 4);
    int*    boff    = (int*)alloc((MAXNB + 1) * 4);
    int*    gcur    = (int*)alloc(MAXNB * 4);
    int*    binned  = (int*)alloc((size_t)E * 4);      // aliased below as A (fp16 n*64)
    int*    csr_src = (int*)alloc((size_t)E * 4);
    float*  dinv    = (float*)alloc((size_t)n * 4);
    float*  B       = (float*)alloc((size_t)n * 64 * 4);
    float*  sums    = (float*)alloc(N_GRAPHS * 64 * 4);
    float*  gcnt    = (float*)alloc(N_GRAPHS * 4);
    short*  w1hi    = (short*)alloc(4 * 4 * 64 * 8 * 2);
    short*  w1lo    = (short*)alloc(4 * 4 * 64 * 8 * 2);
    short*  w2hi    = (short*)alloc(2 * 4 * 64 * 8 * 2);
    short*  w2lo    = (short*)alloc(2 * 4 * 64 * 8 * 2);
    short*  w3hi    = (short*)alloc(2 * 4 * 64 * 8 * 2);
    short*  w3lo    = (short*)alloc(2 * 4 * 64 * 8 * 2);
    __half* A       = (__half*)binned;  // binned dead (after build_csr) before A is written

    int blk = 256;
    int gBin  = (E + CHUNK - 1) / CHUNK;
    int gGemm = (n + 63) / 64;

    // ---- CSR build + weight pack + output-accumulator zeroing ----
    hipMemsetAsync(bcnt, 0, MAXNB * sizeof(int), stream);
    hist_buckets<<<1024, blk, 0, stream>>>(dst, E, NB, bcnt);
    fused_prep<<<12, 1024, 0, stream>>>(bcnt, NB, E, boff, gcur,
                                        W1, w1hi, w1lo, W2, w2hi, w2lo, W3, w3hi, w3lo,
                                        sums, gcnt);
    bin_edges<<<gBin, 1024, 0, stream>>>(src, dst, E, NB, gcur, binned);
    build_csr<<<NB, blk, 0, stream>>>(boff, binned, n, E, rowptr, dinv, csr_src);

    // ---- layer 1 ----
    gemm_mfma<D_IN><<<gGemm, blk, 0, stream>>>(x, w1hi, w1lo, nullptr, 0, A, n);
    gather_agg<<<2048, blk, 0, stream>>>(rowptr, csr_src, dinv, A, B, n);

    // ---- layer 2 ----
    gemm_mfma<D_HID><<<gGemm, blk, 0, stream>>>(B, w2hi, w2lo, b1, 1, A, n);
    gather_agg<<<2048, blk, 0, stream>>>(rowptr, csr_src, dinv, A, B, n);

    // ---- layer 3 ----
    gemm_mfma<D_HID><<<gGemm, blk, 0, stream>>>(B, w3hi, w3lo, b2, 1, A, n);
    gather_agg<<<2048, blk, 0, stream>>>(rowptr, csr_src, dinv, A, B, n);

    // ---- pool + final (b3 folded into final_linear) ----
    {
        int waves = 256 * 256 / 64;
        int chunk = (n + waves - 1) / waves;
        pool_nodes<<<256, blk, 0, stream>>>(B, batch, sums, gcnt, n, chunk);
    }
    final_linear<<<(N_GRAPHS * N_CLASSES + blk - 1) / blk, blk, 0, stream>>>(
        sums, gcnt, b3, Wl, bl, (float*)d_out);
}